// Round 2
// baseline (791.787 us; speedup 1.0000x reference)
//
#include <hip/hip_runtime.h>

#define NTOK 65536
#define BM 128
#define BN 128
#define BK 32
#define LDK 40  // BK + 8-half pad (A tiles): row stride 80B -> reads 2-way = free (m136)

typedef __attribute__((ext_vector_type(8))) short short8;
typedef __attribute__((ext_vector_type(4))) float f32x4;
typedef __attribute__((ext_vector_type(4))) unsigned int u32x4;

// ws layout: [0,64) 16 ints (counts/offsets/cursors); [64, 64+NTOK*4) sorted ids;
// [512K, 512K+8M) w_hi bf16 swizzled tiles; [+8M, +16M) w_lo.
#define WS_WHI_OFF (512u * 1024u)
#define WS_WLO_OFF (512u * 1024u + 8u * 1024u * 1024u)
#define WS_NEED    (512u * 1024u + 16u * 1024u * 1024u)

// ---------- bf16 truncation split: f = hi + lo + O(2^-14 * f) ----------
__device__ __forceinline__ void split2(float f0, float f1, unsigned int& h, unsigned int& l) {
    unsigned int b0 = __float_as_uint(f0), b1 = __float_as_uint(f1);
    unsigned int h0 = b0 & 0xFFFF0000u, h1 = b1 & 0xFFFF0000u;
    h = (h0 >> 16) | h1;                       // [lo16]=bf16(f0) [hi16]=bf16(f1)
    float r0 = f0 - __uint_as_float(h0);       // exact residual (same-binade subtract)
    float r1 = f1 - __uint_as_float(h1);
    unsigned int rb0 = __float_as_uint(r0), rb1 = __float_as_uint(r1);
    rb0 += 0x7FFFu + ((rb0 >> 16) & 1u);       // RNE to bf16
    rb1 += 0x7FFFu + ((rb1 >> 16) & 1u);
    l = (rb0 >> 16) | (rb1 & 0xFFFF0000u);
}

__device__ __forceinline__ void gload_lds16(const void* g, void* l) {
    __builtin_amdgcn_global_load_lds((const __attribute__((address_space(1))) void*)g,
                                     (__attribute__((address_space(3))) void*)l, 16, 0, 0);
}

// ---------------- sorting ----------------
__global__ void k_init(int* ws) {
    if (threadIdx.x < 16) ws[threadIdx.x] = 0;
}

__device__ __forceinline__ int branch_of(int v) { return 31 - __clz(v) - 7; } // 128..1024 -> 0..3

__global__ void k_hist(const int* __restrict__ ofs, int* __restrict__ ws) {
    int t = blockIdx.x * blockDim.x + threadIdx.x;
    int b = branch_of(ofs[t]);
    int lane = threadIdx.x & 63;
    unsigned long long below = (lane == 63) ? ~0ull >> 1 : ((1ull << (lane + 1)) - 1) >> 1;
#pragma unroll
    for (int bb = 0; bb < 4; ++bb) {
        unsigned long long m = __ballot(b == bb);
        if (b == bb && (m & below) == 0)
            atomicAdd(&ws[bb], (int)__popcll(m));
    }
}

__global__ void k_offs(int* ws) {
    if (threadIdx.x == 0) {
        int acc = 0;
        for (int b = 0; b < 4; ++b) { ws[4 + b] = acc; acc += ws[b]; }
    }
}

__global__ void k_scatter(const int* __restrict__ ofs, int* __restrict__ ws) {
    int t = blockIdx.x * blockDim.x + threadIdx.x;
    int b = branch_of(ofs[t]);
    int lane = threadIdx.x & 63;
    unsigned long long below = (lane == 63) ? ~0ull >> 1 : ((1ull << (lane + 1)) - 1) >> 1;
#pragma unroll
    for (int bb = 0; bb < 4; ++bb) {
        unsigned long long m = __ballot(b == bb);
        if (b == bb) {
            int rank = (int)__popcll(m & below);
            int base = 0;
            if (rank == 0) base = atomicAdd(&ws[8 + bb], (int)__popcll(m));
            int leader = (int)(__ffsll((long long)m) - 1);
            base = __shfl(base, leader, 64);
            ws[16 + ws[4 + bb] + base + rank] = t;
        }
    }
}

// ---------------- zero tails [sz,1024) ----------------
__global__ void k_ztail(const int* __restrict__ ofs, float* __restrict__ out) {
    int gw = (blockIdx.x * blockDim.x + threadIdx.x) >> 6;
    int lane = threadIdx.x & 63;
    int nw = (gridDim.x * blockDim.x) >> 6;
    f32x4 z = {0.f, 0.f, 0.f, 0.f};
    for (int t = gw; t < NTOK; t += nw) {
        int sz = ofs[t];
        float* p = out + ((size_t)t << 10);
        for (int c = sz + lane * 4; c < 1024; c += 256)
            *(f32x4*)(p + c) = z;
    }
}

// ---------------- weight pre-split into swizzled bf16 tiles ----------------
// Tile (b,nt,kt): 128 rows x 32 k halves, stored with 16B-slot XOR swizzle:
// element (rr,kk) at tile*4096 + rr*32 + ((kk>>3)^(rr&3))*8 + (kk&7).
// GEMM reads with the same XOR -> 2-way bank aliasing only (free).
__global__ void k_wsplit(const float* __restrict__ w, unsigned short* __restrict__ wHi,
                         unsigned short* __restrict__ wLo) {
    int tid = blockIdx.x * 256 + threadIdx.x;   // [0, 4*1024*128)
    int s = tid & 127;                          // 8-k slot within row
    int r = (tid >> 7) & 1023;
    int b = tid >> 17;
    const float* src = w + ((((size_t)b << 10) + r) << 10) + s * 8;
    f32x4 v0 = *(const f32x4*)src;
    f32x4 v1 = *(const f32x4*)(src + 4);
    unsigned int h[4], l[4];
    split2(v0[0], v0[1], h[0], l[0]);
    split2(v0[2], v0[3], h[1], l[1]);
    split2(v1[0], v1[1], h[2], l[2]);
    split2(v1[2], v1[3], h[3], l[3]);
    int nt = r >> 7, rr = r & 127;
    int kt = s >> 2, slot = s & 3;
    int slotp = slot ^ (rr & 3);
    size_t base = ((size_t)((b * 8 + nt) * 32 + kt) << 12) + rr * 32 + slotp * 8;
    *(u32x4*)&wHi[base] = (u32x4){h[0], h[1], h[2], h[3]};
    *(u32x4*)&wLo[base] = (u32x4){l[0], l[1], l[2], l[3]};
}

// ---------------- grouped GEMM, bf16 hi/lo split, 3-term MFMA ----------------
template <bool PS>
__global__ __launch_bounds__(256, 2)
void k_gemm(const float* __restrict__ x, const float* __restrict__ w,
            const unsigned short* __restrict__ wHi, const unsigned short* __restrict__ wLo,
            const float* __restrict__ bias, const int* __restrict__ wsI,
            float* __restrict__ out) {
    int bid = blockIdx.x;
    int br, local, ntl;
    if (bid < 512)       { br = 0; local = bid;        ntl = 0; }
    else if (bid < 1536) { br = 1; local = bid - 512;  ntl = 1; }
    else if (bid < 3584) { br = 2; local = bid - 1536; ntl = 2; }
    else                 { br = 3; local = bid - 3584; ntl = 3; }
    // mt-major: blocks sharing the same A-panel (same mt, all nt) are adjacent -> L2/L3 hits
    const int mt = local >> ntl;
    const int nt = local & ((1 << ntl) - 1);
    const int Mb = wsI[br];
    if (mt * BM >= Mb) return;
    const int sbase = wsI[4 + br];
    const int* sorted = wsI + 16;

    __shared__ unsigned short lds[2][4][BM * LDK];  // 80 KB -> 2 blocks/CU

    const int t = threadIdx.x;
    const int lane = t & 63;
    const int wv = t >> 6;
    const int wm = wv >> 1, wn = wv & 1;

    // A staging: thread owns (row = t>>1, 16-k half = t&1)
    const int srow = t >> 1;
    const int skh = (t & 1) * 16;
    int gr0 = mt * BM + srow;
    int tok0 = sorted[sbase + (gr0 < Mb ? gr0 : Mb - 1)];
    const float* pA = x + ((size_t)tok0 << 10) + skh;
    const float* pB = w + ((size_t)br << 20) + (((size_t)(nt * BN + srow)) << 10) + skh;

    f32x4 ra[4], rb[4];
    f32x4 acc[4][4];
#pragma unroll
    for (int m = 0; m < 4; ++m)
#pragma unroll
        for (int n = 0; n < 4; ++n) acc[m][n] = (f32x4){0.f, 0.f, 0.f, 0.f};

    auto loadRegs = [&](int kt) {
        const float* a = pA + kt * BK;
#pragma unroll
        for (int i = 0; i < 4; ++i) ra[i] = *(const f32x4*)(a + i * 4);
        if constexpr (!PS) {
            const float* b = pB + kt * BK;
#pragma unroll
            for (int i = 0; i < 4; ++i) rb[i] = *(const f32x4*)(b + i * 4);
        }
    };

    auto dmaB = [&](int kt) {  // PS only: 2x 8KB swizzled tiles ws -> LDS, zero VALU
        if constexpr (PS) {
            const int buf = kt & 1;
            const size_t tb = ((size_t)((br * 8 + nt) * 32 + kt)) << 13;  // byte base
            const char* sH = (const char*)wHi + tb;
            const char* sL = (const char*)wLo + tb;
            char* dH = (char*)&lds[buf][2][0];
            char* dL = (char*)&lds[buf][3][0];
            const int wo = wv * 2048;
#pragma unroll
            for (int j = 0; j < 2; ++j) {
                gload_lds16(sH + wo + j * 1024 + lane * 16, dH + wo + j * 1024);
                gload_lds16(sL + wo + j * 1024 + lane * 16, dL + wo + j * 1024);
            }
        }
    };

    auto writeStage = [&](int buf) {
        unsigned int h[8], l[8];
#pragma unroll
        for (int j = 0; j < 8; ++j)
            split2(ra[j >> 1][(j & 1) * 2], ra[j >> 1][(j & 1) * 2 + 1], h[j], l[j]);
        const int base = srow * LDK + skh;
        *(u32x4*)&lds[buf][0][base]     = (u32x4){h[0], h[1], h[2], h[3]};
        *(u32x4*)&lds[buf][0][base + 8] = (u32x4){h[4], h[5], h[6], h[7]};
        *(u32x4*)&lds[buf][1][base]     = (u32x4){l[0], l[1], l[2], l[3]};
        *(u32x4*)&lds[buf][1][base + 8] = (u32x4){l[4], l[5], l[6], l[7]};
        if constexpr (!PS) {
#pragma unroll
            for (int j = 0; j < 8; ++j)
                split2(rb[j >> 1][(j & 1) * 2], rb[j >> 1][(j & 1) * 2 + 1], h[j], l[j]);
            *(u32x4*)&lds[buf][2][base]     = (u32x4){h[0], h[1], h[2], h[3]};
            *(u32x4*)&lds[buf][2][base + 8] = (u32x4){h[4], h[5], h[6], h[7]};
            *(u32x4*)&lds[buf][3][base]     = (u32x4){l[0], l[1], l[2], l[3]};
            *(u32x4*)&lds[buf][3][base + 8] = (u32x4){l[4], l[5], l[6], l[7]};
        }
    };

    auto compute = [&](int buf) {
        const unsigned short* Ah = lds[buf][0];
        const unsigned short* Al = lds[buf][1];
        const unsigned short* Bh = lds[buf][2];
        const unsigned short* Bl = lds[buf][3];
        const int lr = lane & 15;
        const int g = lane >> 4;
        short8 fbh[4], fbl[4];
#pragma unroll
        for (int n = 0; n < 4; ++n) {
            const int row = wn * 64 + n * 16 + lr;
            const int off = PS ? (row * 32 + ((g ^ (row & 3)) << 3))   // swizzled [128][32]
                               : (row * LDK + g * 8);                  // padded
            fbh[n] = *(const short8*)&Bh[off];
            fbl[n] = *(const short8*)&Bl[off];
        }
#pragma unroll
        for (int m = 0; m < 4; ++m) {
            const int off = (wm * 64 + m * 16 + lr) * LDK + g * 8;
            short8 fah = *(const short8*)&Ah[off];
            short8 fal = *(const short8*)&Al[off];
#pragma unroll
            for (int n = 0; n < 4; ++n) {
                acc[m][n] = __builtin_amdgcn_mfma_f32_16x16x32_bf16(fah, fbh[n], acc[m][n], 0, 0, 0);
                acc[m][n] = __builtin_amdgcn_mfma_f32_16x16x32_bf16(fah, fbl[n], acc[m][n], 0, 0, 0);
                acc[m][n] = __builtin_amdgcn_mfma_f32_16x16x32_bf16(fal, fbh[n], acc[m][n], 0, 0, 0);
            }
        }
    };

    const int NT = 1024 / BK;  // 32
    dmaB(0);
    loadRegs(0);
    writeStage(0);
    loadRegs(1);
    __syncthreads();  // drains vmcnt -> buf0 B ready
    for (int kt = 0; kt < NT; ++kt) {
        if (kt + 1 < NT) dmaB(kt + 1);           // buf (kt+1)&1: all reads of it done pre-barrier(kt-1)
        compute(kt & 1);
        if (kt + 1 < NT) {
            writeStage((kt + 1) & 1);            // consumes regs loaded last iter
            if (kt + 2 < NT) loadRegs(kt + 2);
            __syncthreads();
        }
    }

    // epilogue: C layout col=lane&15, row=(lane>>4)*4+j (m89)
    const int lr = lane & 15;
    const int rg = (lane >> 4) * 4;
#pragma unroll
    for (int n = 0; n < 4; ++n) {
        int col = nt * BN + wn * 64 + n * 16 + lr;
        float bv = bias[(br << 10) + col];
#pragma unroll
        for (int m = 0; m < 4; ++m) {
            int r0 = mt * BM + wm * 64 + m * 16 + rg;
#pragma unroll
            for (int j = 0; j < 4; ++j) {
                int r = r0 + j;
                if (r < Mb) {
                    int tk = sorted[sbase + r];
                    out[((size_t)tk << 10) + col] = acc[m][n][j] + bv;
                }
            }
        }
    }
}

extern "C" void kernel_launch(void* const* d_in, const int* in_sizes, int n_in,
                              void* d_out, int out_size, void* d_ws, size_t ws_size,
                              hipStream_t stream) {
    const float* x    = (const float*)d_in[0];
    const float* wgt  = (const float*)d_in[1];
    const float* bias = (const float*)d_in[2];
    const int*   ofs  = (const int*)d_in[3];
    float* out = (float*)d_out;
    int* wsI = (int*)d_ws;
    unsigned short* wHi = (unsigned short*)((char*)d_ws + WS_WHI_OFF);
    unsigned short* wLo = (unsigned short*)((char*)d_ws + WS_WLO_OFF);
    const bool ps = ws_size >= (size_t)WS_NEED;

    k_init<<<1, 64, 0, stream>>>(wsI);
    k_hist<<<NTOK / 256, 256, 0, stream>>>(ofs, wsI);
    k_offs<<<1, 64, 0, stream>>>(wsI);
    k_scatter<<<NTOK / 256, 256, 0, stream>>>(ofs, wsI);
    if (ps) k_wsplit<<<2048, 256, 0, stream>>>(wgt, wHi, wLo);
    k_ztail<<<512, 256, 0, stream>>>(ofs, out);
    // worst-case grid: 512 m-tiles per branch x {1,2,4,8} n-tiles = 7680
    if (ps) k_gemm<true><<<7680, 256, 0, stream>>>(x, wgt, wHi, wLo, bias, wsI, out);
    else    k_gemm<false><<<7680, 256, 0, stream>>>(x, wgt, wHi, wLo, bias, wsI, out);
}

// Round 3
// 785.887 us; speedup vs baseline: 1.0075x; 1.0075x over previous
//
#include <hip/hip_runtime.h>

#define NTOK 65536
#define BM 128
#define BN 128
#define BK 32
#define LDK 40  // BK + 8-half pad: 80B row stride -> uniform bank-chunk spread (A verified low-conflict r2)

typedef __attribute__((ext_vector_type(8))) short short8;
typedef __attribute__((ext_vector_type(4))) float f32x4;
typedef __attribute__((ext_vector_type(4))) unsigned int u32x4;

// ws layout: [0,64) 16 ints; [64, 64+NTOK*4) sorted ids;
// padded bf16 tiles: hi at +512K (10 MB), lo after (10 MB). Tile = 128 rows x 40 halves = 10240 B.
#define TILE_B   10240u
#define WS_WHI_OFF (512u * 1024u)
#define WS_WLO_OFF (512u * 1024u + 10485760u)
#define WS_NEED    (512u * 1024u + 2u * 10485760u)

// ---------- bf16 truncation split: f = hi + lo + O(2^-17 * f) ----------
__device__ __forceinline__ void split2(float f0, float f1, unsigned int& h, unsigned int& l) {
    unsigned int b0 = __float_as_uint(f0), b1 = __float_as_uint(f1);
    unsigned int h0 = b0 & 0xFFFF0000u, h1 = b1 & 0xFFFF0000u;
    h = (h0 >> 16) | h1;
    float r0 = f0 - __uint_as_float(h0);   // exact residual
    float r1 = f1 - __uint_as_float(h1);
    unsigned int rb0 = __float_as_uint(r0), rb1 = __float_as_uint(r1);
    rb0 += 0x7FFFu + ((rb0 >> 16) & 1u);   // RNE to bf16
    rb1 += 0x7FFFu + ((rb1 >> 16) & 1u);
    l = (rb0 >> 16) | (rb1 & 0xFFFF0000u);
}

__device__ __forceinline__ void gload_lds16(const void* g, void* l) {
    __builtin_amdgcn_global_load_lds((const __attribute__((address_space(1))) void*)g,
                                     (__attribute__((address_space(3))) void*)l, 16, 0, 0);
}

// ---------------- sorting ----------------
__global__ void k_init(int* ws) {
    if (threadIdx.x < 16) ws[threadIdx.x] = 0;
}

__device__ __forceinline__ int branch_of(int v) { return 31 - __clz(v) - 7; } // 128..1024 -> 0..3

__global__ void k_hist(const int* __restrict__ ofs, int* __restrict__ ws) {
    int t = blockIdx.x * blockDim.x + threadIdx.x;
    int b = branch_of(ofs[t]);
    int lane = threadIdx.x & 63;
    unsigned long long below = (lane == 63) ? ~0ull >> 1 : ((1ull << (lane + 1)) - 1) >> 1;
#pragma unroll
    for (int bb = 0; bb < 4; ++bb) {
        unsigned long long m = __ballot(b == bb);
        if (b == bb && (m & below) == 0)
            atomicAdd(&ws[bb], (int)__popcll(m));
    }
}

// scatter computes branch offsets locally from counts (k_offs eliminated)
__global__ void k_scatter(const int* __restrict__ ofs, int* __restrict__ ws) {
    int t = blockIdx.x * blockDim.x + threadIdx.x;
    int b = branch_of(ofs[t]);
    int c0 = ws[0], c1 = ws[1], c2 = ws[2];
    int boff[4] = {0, c0, c0 + c1, c0 + c1 + c2};
    int lane = threadIdx.x & 63;
    unsigned long long below = (lane == 63) ? ~0ull >> 1 : ((1ull << (lane + 1)) - 1) >> 1;
#pragma unroll
    for (int bb = 0; bb < 4; ++bb) {
        unsigned long long m = __ballot(b == bb);
        if (b == bb) {
            int rank = (int)__popcll(m & below);
            int base = 0;
            if (rank == 0) base = atomicAdd(&ws[8 + bb], (int)__popcll(m));
            int leader = (int)(__ffsll((long long)m) - 1);
            base = __shfl(base, leader, 64);
            ws[16 + boff[bb] + base + rank] = t;
        }
    }
}

// ---------------- zero tails [sz,1024) ----------------
__global__ void k_ztail(const int* __restrict__ ofs, float* __restrict__ out) {
    int gw = (blockIdx.x * blockDim.x + threadIdx.x) >> 6;
    int lane = threadIdx.x & 63;
    int nw = (gridDim.x * blockDim.x) >> 6;
    f32x4 z = {0.f, 0.f, 0.f, 0.f};
    for (int t = gw; t < NTOK; t += nw) {
        int sz = ofs[t];
        float* p = out + ((size_t)t << 10);
        for (int c = sz + lane * 4; c < 1024; c += 256)
            *(f32x4*)(p + c) = z;
    }
}

// ---------------- weight pre-split into PADDED bf16 tiles (no swizzle) ----------------
// Tile (b,nt,kt): [128 rows][40 halves], element (rr, kk) at rr*40 + kk (kk<32); pad never read.
__global__ void k_wsplit(const float* __restrict__ w, unsigned short* __restrict__ wHi,
                         unsigned short* __restrict__ wLo) {
    int tid = blockIdx.x * 256 + threadIdx.x;
    int s = tid & 127;                       // 8-k slot within row
    int r = (tid >> 7) & 1023;
    int b = tid >> 17;
    const float* src = w + ((((size_t)b << 10) + r) << 10) + s * 8;
    f32x4 v0 = *(const f32x4*)src;
    f32x4 v1 = *(const f32x4*)(src + 4);
    unsigned int h[4], l[4];
    split2(v0[0], v0[1], h[0], l[0]);
    split2(v0[2], v0[3], h[1], l[1]);
    split2(v1[0], v1[1], h[2], l[2]);
    split2(v1[2], v1[3], h[3], l[3]);
    int nt = r >> 7, rr = r & 127;
    int kt = s >> 2, slot = s & 3;
    size_t base = (size_t)((b * 8 + nt) * 32 + kt) * (TILE_B / 2) + rr * LDK + slot * 8;
    *(u32x4*)&wHi[base] = (u32x4){h[0], h[1], h[2], h[3]};
    *(u32x4*)&wLo[base] = (u32x4){l[0], l[1], l[2], l[3]};
}

// ---------------- grouped GEMM, bf16 hi/lo split, 3-term MFMA ----------------
template <bool PS>
__global__ __launch_bounds__(256, 2)
void k_gemm(const float* __restrict__ x, const float* __restrict__ w,
            const unsigned short* __restrict__ wHi, const unsigned short* __restrict__ wLo,
            const float* __restrict__ bias, const int* __restrict__ wsI,
            float* __restrict__ out) {
    // XCD-balanced decode: pair (br,mt) -> xcd = mt&7; nt-mates adjacent on same XCD.
    const int xcd = blockIdx.x & 7;
    const int slot = blockIdx.x >> 3;   // [0,960)
    int br, pi, nt;
    if (slot < 64)       { br = 0; pi = slot;              nt = 0; }
    else if (slot < 192) { br = 1; pi = (slot - 64) >> 1;  nt = (slot - 64) & 1; }
    else if (slot < 448) { br = 2; pi = (slot - 192) >> 2; nt = (slot - 192) & 3; }
    else                 { br = 3; pi = (slot - 448) >> 3; nt = (slot - 448) & 7; }
    const int mt = pi * 8 + xcd;

    const int c0 = wsI[0], c1 = wsI[1], c2 = wsI[2], c3 = wsI[3];
    const int cnt[4] = {c0, c1, c2, c3};
    const int offs[4] = {0, c0, c0 + c1, c0 + c1 + c2};
    const int Mb = cnt[br];
    if (mt * BM >= Mb) return;
    const int sbase = offs[br];
    const int* sorted = wsI + 16;

    __shared__ unsigned short lds[2][4][BM * LDK];  // [buf][Ah,Al,Bh,Bl] = 80 KB -> 2 blocks/CU

    const int t = threadIdx.x;
    const int lane = t & 63;
    const int wv = t >> 6;
    const int wm = wv >> 1, wn = wv & 1;

    // A staging: thread owns (row = t>>1, 16-k half = t&1)
    const int srow = t >> 1;
    const int skh = (t & 1) * 16;
    int gr0 = mt * BM + srow;
    int tok0 = sorted[sbase + (gr0 < Mb ? gr0 : Mb - 1)];
    const float* pA = x + ((size_t)tok0 << 10) + skh;
    const float* pB = w + ((size_t)br << 20) + (((size_t)(nt * BN + srow)) << 10) + skh;

    f32x4 acc[4][4];
#pragma unroll
    for (int m = 0; m < 4; ++m)
#pragma unroll
        for (int n = 0; n < 4; ++n) acc[m][n] = (f32x4){0.f, 0.f, 0.f, 0.f};

    auto loadRA = [&](f32x4* r, int kt) {
        const float* a = pA + kt * BK;
#pragma unroll
        for (int i = 0; i < 4; ++i) r[i] = *(const f32x4*)(a + i * 4);
    };

    auto dmaB = [&](int kt, int buf) {  // PS: 2x10KB padded tiles ws->LDS, 5 chunks/wave
        const size_t tb = (size_t)((br * 8 + nt) * 32 + kt) * TILE_B;
        const char* sH = (const char*)wHi + tb;
        const char* sL = (const char*)wLo + tb;
        char* dH = (char*)&lds[buf][2][0];
        char* dL = (char*)&lds[buf][3][0];
#pragma unroll
        for (int i = 0; i < 5; ++i) {
            int c = wv + 4 * i;  // wave-uniform, 0..19
            const char* s = (c < 10) ? sH + c * 1024 : sL + (c - 10) * 1024;
            char* d = (c < 10) ? dH + c * 1024 : dL + (c - 10) * 1024;
            gload_lds16(s + lane * 16, d);
        }
    };

    auto writeA = [&](int buf, const f32x4* r) {
        unsigned int h[8], l[8];
#pragma unroll
        for (int j = 0; j < 8; ++j)
            split2(r[j >> 1][(j & 1) * 2], r[j >> 1][(j & 1) * 2 + 1], h[j], l[j]);
        const int base = srow * LDK + skh;
        *(u32x4*)&lds[buf][0][base]     = (u32x4){h[0], h[1], h[2], h[3]};
        *(u32x4*)&lds[buf][0][base + 8] = (u32x4){h[4], h[5], h[6], h[7]};
        *(u32x4*)&lds[buf][1][base]     = (u32x4){l[0], l[1], l[2], l[3]};
        *(u32x4*)&lds[buf][1][base + 8] = (u32x4){l[4], l[5], l[6], l[7]};
    };

    auto writeB = [&](int buf, const f32x4* r) {  // !PS fallback only
        unsigned int h[8], l[8];
#pragma unroll
        for (int j = 0; j < 8; ++j)
            split2(r[j >> 1][(j & 1) * 2], r[j >> 1][(j & 1) * 2 + 1], h[j], l[j]);
        const int base = srow * LDK + skh;
        *(u32x4*)&lds[buf][2][base]     = (u32x4){h[0], h[1], h[2], h[3]};
        *(u32x4*)&lds[buf][2][base + 8] = (u32x4){h[4], h[5], h[6], h[7]};
        *(u32x4*)&lds[buf][3][base]     = (u32x4){l[0], l[1], l[2], l[3]};
        *(u32x4*)&lds[buf][3][base + 8] = (u32x4){l[4], l[5], l[6], l[7]};
    };

    auto compute = [&](int buf) {
        const unsigned short* Ah = lds[buf][0];
        const unsigned short* Al = lds[buf][1];
        const unsigned short* Bh = lds[buf][2];
        const unsigned short* Bl = lds[buf][3];
        const int lr = lane & 15;
        const int g = lane >> 4;
        short8 fbh[4], fbl[4];
#pragma unroll
        for (int n = 0; n < 4; ++n) {
            const int off = (wn * 64 + n * 16 + lr) * LDK + g * 8;
            fbh[n] = *(const short8*)&Bh[off];
            fbl[n] = *(const short8*)&Bl[off];
        }
#pragma unroll
        for (int m = 0; m < 4; ++m) {
            const int off = (wm * 64 + m * 16 + lr) * LDK + g * 8;
            short8 fah = *(const short8*)&Ah[off];
            short8 fal = *(const short8*)&Al[off];
#pragma unroll
            for (int n = 0; n < 4; ++n) {
                acc[m][n] = __builtin_amdgcn_mfma_f32_16x16x32_bf16(fah, fbh[n], acc[m][n], 0, 0, 0);
                acc[m][n] = __builtin_amdgcn_mfma_f32_16x16x32_bf16(fah, fbl[n], acc[m][n], 0, 0, 0);
                acc[m][n] = __builtin_amdgcn_mfma_f32_16x16x32_bf16(fal, fbh[n], acc[m][n], 0, 0, 0);
            }
        }
    };

    if constexpr (PS) {
        f32x4 ra0[4], ra1[4];
        // prologue: stage kt=0 into buf0, preload A(1)
        dmaB(0, 0);
        loadRA(ra0, 0);
        writeA(0, ra0);
        loadRA(ra1, 1);
        __syncthreads();
        // steady: iter kt: {dmaB(kt+1) | loadRA(kt+2) | compute(kt) | writeA(kt+1) | barrier}
        // loads issued ~a full compute before the barrier's vmcnt(0) drain (T14).
        for (int tt = 0; tt < 15; ++tt) {
            dmaB(2 * tt + 1, 1);
            loadRA(ra0, 2 * tt + 2);
            compute(0);
            writeA(1, ra1);
            __syncthreads();
            dmaB(2 * tt + 2, 0);
            loadRA(ra1, 2 * tt + 3);
            compute(1);
            writeA(0, ra0);
            __syncthreads();
        }
        dmaB(31, 1);
        compute(0);       // kt=30
        writeA(1, ra1);
        __syncthreads();
        compute(1);       // kt=31
    } else {
        // fallback: split both A and B in-loop (no ws staging)
        f32x4 ra[4], rb[4];
        auto loadB = [&](f32x4* r, int kt) {
            const float* b = pB + kt * BK;
#pragma unroll
            for (int i = 0; i < 4; ++i) r[i] = *(const f32x4*)(b + i * 4);
        };
        loadRA(ra, 0); loadB(rb, 0);
        writeA(0, ra); writeB(0, rb);
        __syncthreads();
        for (int kt = 0; kt < 32; ++kt) {
            if (kt + 1 < 32) { loadRA(ra, kt + 1); loadB(rb, kt + 1); }
            compute(kt & 1);
            if (kt + 1 < 32) {
                writeA((kt + 1) & 1, ra); writeB((kt + 1) & 1, rb);
                __syncthreads();
            }
        }
    }

    // epilogue: C layout col=lane&15, row=(lane>>4)*4+j (m89)
    const int lr = lane & 15;
    const int rg = (lane >> 4) * 4;
#pragma unroll
    for (int n = 0; n < 4; ++n) {
        int col = nt * BN + wn * 64 + n * 16 + lr;
        float bv = bias[(br << 10) + col];
#pragma unroll
        for (int m = 0; m < 4; ++m) {
            int r0 = mt * BM + wm * 64 + m * 16 + rg;
#pragma unroll
            for (int j = 0; j < 4; ++j) {
                int r = r0 + j;
                if (r < Mb) {
                    int tk = sorted[sbase + r];
                    out[((size_t)tk << 10) + col] = acc[m][n][j] + bv;
                }
            }
        }
    }
}

extern "C" void kernel_launch(void* const* d_in, const int* in_sizes, int n_in,
                              void* d_out, int out_size, void* d_ws, size_t ws_size,
                              hipStream_t stream) {
    const float* x    = (const float*)d_in[0];
    const float* wgt  = (const float*)d_in[1];
    const float* bias = (const float*)d_in[2];
    const int*   ofs  = (const int*)d_in[3];
    float* out = (float*)d_out;
    int* wsI = (int*)d_ws;
    unsigned short* wHi = (unsigned short*)((char*)d_ws + WS_WHI_OFF);
    unsigned short* wLo = (unsigned short*)((char*)d_ws + WS_WLO_OFF);
    const bool ps = ws_size >= (size_t)WS_NEED;

    k_init<<<1, 64, 0, stream>>>(wsI);
    k_hist<<<NTOK / 256, 256, 0, stream>>>(ofs, wsI);
    k_scatter<<<NTOK / 256, 256, 0, stream>>>(ofs, wsI);
    if (ps) k_wsplit<<<2048, 256, 0, stream>>>(wgt, wHi, wLo);
    k_ztail<<<512, 256, 0, stream>>>(ofs, out);
    if (ps) k_gemm<true><<<7680, 256, 0, stream>>>(x, wgt, wHi, wLo, bias, wsI, out);
    else    k_gemm<false><<<7680, 256, 0, stream>>>(x, wgt, wHi, wLo, bias, wsI, out);
}